// Round 1
// baseline (721.840 us; speedup 1.0000x reference)
//
#include <hip/hip_runtime.h>
#include <hip/hip_bf16.h>

#define Bn 32
#define Sn 2048
#define Hn 2048
#define Qn 1024
#define Mn (Bn * Sn)

#define BM 128
#define BN 128
#define BK 32

typedef __attribute__((ext_vector_type(8))) short bf16x8;
typedef __attribute__((ext_vector_type(4))) float f32x4;

__device__ __forceinline__ unsigned short f2bf(float x) {
  unsigned int u = __float_as_uint(x);
  unsigned int r = (u + 0x7FFFu + ((u >> 16) & 1u)) >> 16;  // RNE
  return (unsigned short)r;
}

// ---------------- c1[b,q] = sum_k rev[b,k] * Wa[q,k] (one wave per output) ---
__global__ void c1_kernel(const float* __restrict__ rev,
                          const float* __restrict__ Wa,
                          float* __restrict__ c1) {
  int wid = (blockIdx.x * 256 + threadIdx.x) >> 6;
  int lane = threadIdx.x & 63;
  int b = wid >> 10;
  int q = wid & (Qn - 1);
  const float* rv = rev + (size_t)b * Qn;
  const float* wr = Wa + (size_t)q * Qn;
  float acc = 0.f;
#pragma unroll
  for (int k = 0; k < Qn; k += 64) acc += rv[k + lane] * wr[k + lane];
#pragma unroll
  for (int m = 32; m > 0; m >>= 1) acc += __shfl_xor(acc, m, 64);
  if (lane == 0) c1[wid] = acc;
}

// ---------------- Ua f32 -> bf16 ------------------------------------------
__global__ void cvt_ua_kernel(const float* __restrict__ Ua,
                              unsigned short* __restrict__ out) {
  int i = blockIdx.x * 256 + threadIdx.x;  // each handles 4 elements
  float4 v = ((const float4*)Ua)[i];
  union { bf16x8 v8; unsigned short u[8]; } pk;  // only first 4 used
  pk.u[0] = f2bf(v.x); pk.u[1] = f2bf(v.y);
  pk.u[2] = f2bf(v.z); pk.u[3] = f2bf(v.w);
  typedef __attribute__((ext_vector_type(4))) unsigned short u16x4;
  u16x4 o = {pk.u[0], pk.u[1], pk.u[2], pk.u[3]};
  *(u16x4*)(out + (size_t)i * 4) = o;
}

// ---------------- main GEMM + fused tanh/Va epilogue -----------------------
// A = rnn [Mn, Hn] f32 ; Bmat = Ua_bf16 [Qn, Hn] ; e[m] += sum_q Va[q]*tanh(c1+acc)
__global__ __launch_bounds__(256) void gemm_e_kernel(
    const float* __restrict__ A, const unsigned short* __restrict__ Bmat,
    const float* __restrict__ c1, const float* __restrict__ Va,
    float* __restrict__ e) {
  __shared__ unsigned short As[BM * BK];
  __shared__ unsigned short Bs[BN * BK];
  __shared__ float c1s[BN];
  __shared__ float Vas[BN];

  const int t = threadIdx.x;
  const int lane = t & 63;
  const int w = t >> 6;
  const int n0 = blockIdx.x * BN;
  const int m0 = blockIdx.y * BM;
  const int bidx = m0 >> 11;  // batch index (BM=128 divides S=2048, never straddles)

  if (t < BN) {
    c1s[t] = c1[bidx * Qn + n0 + t];
    Vas[t] = Va[n0 + t];
  }

  const int wm = (w >> 1) * 64;
  const int wn = (w & 1) * 64;
  const int lrow = lane & 15;
  const int lk16 = (lane >> 4) * 16;  // k byte offset within a 64B row

  int a_off[4], b_off[4];
#pragma unroll
  for (int i = 0; i < 4; i++) {
    int r = wm + i * 16 + lrow;
    a_off[i] = (r * 64 + lk16) ^ ((r & 7) << 4);
    int r2 = wn + i * 16 + lrow;
    b_off[i] = (r2 * 64 + lk16) ^ ((r2 & 7) << 4);
  }

  const int srow = t >> 2;        // staging row within half (0..63)
  const int sk = (t & 3) * 8;     // staging k element offset

  f32x4 acc[4][4];
#pragma unroll
  for (int i = 0; i < 4; i++)
#pragma unroll
    for (int j = 0; j < 4; j++) acc[i][j] = (f32x4){0.f, 0.f, 0.f, 0.f};

  char* Asb = (char*)As;
  char* Bsb = (char*)Bs;

  for (int kb = 0; kb < Hn; kb += BK) {
    __syncthreads();
    // stage A (f32 -> bf16, swizzled)
#pragma unroll
    for (int half = 0; half < 2; half++) {
      int row = srow + half * 64;
      const float* g = A + (size_t)(m0 + row) * Hn + kb + sk;
      float4 v0 = *(const float4*)g;
      float4 v1 = *(const float4*)(g + 4);
      union { bf16x8 v8; unsigned short u[8]; } pk;
      pk.u[0] = f2bf(v0.x); pk.u[1] = f2bf(v0.y);
      pk.u[2] = f2bf(v0.z); pk.u[3] = f2bf(v0.w);
      pk.u[4] = f2bf(v1.x); pk.u[5] = f2bf(v1.y);
      pk.u[6] = f2bf(v1.z); pk.u[7] = f2bf(v1.w);
      int off = (row * 64 + sk * 2) ^ ((row & 7) << 4);
      *(bf16x8*)(Asb + off) = pk.v8;
    }
    // stage B (bf16 copy, swizzled)
#pragma unroll
    for (int half = 0; half < 2; half++) {
      int row = srow + half * 64;
      const unsigned short* g = Bmat + (size_t)(n0 + row) * Hn + kb + sk;
      bf16x8 v = *(const bf16x8*)g;
      int off = (row * 64 + sk * 2) ^ ((row & 7) << 4);
      *(bf16x8*)(Bsb + off) = v;
    }
    __syncthreads();

    bf16x8 af[4], bfr[4];
#pragma unroll
    for (int i = 0; i < 4; i++) af[i] = *(const bf16x8*)(Asb + a_off[i]);
#pragma unroll
    for (int j = 0; j < 4; j++) bfr[j] = *(const bf16x8*)(Bsb + b_off[j]);
#pragma unroll
    for (int i = 0; i < 4; i++)
#pragma unroll
      for (int j = 0; j < 4; j++)
        acc[i][j] = __builtin_amdgcn_mfma_f32_16x16x32_bf16(af[i], bfr[j],
                                                            acc[i][j], 0, 0, 0);
  }

  // epilogue: e[row] += sum over this block's 128 q of Va*tanh(c1+c2)
#pragma unroll
  for (int i = 0; i < 4; i++) {
#pragma unroll
    for (int r = 0; r < 4; r++) {
      float sum = 0.f;
#pragma unroll
      for (int j = 0; j < 4; j++) {
        int ql = wn + j * 16 + lrow;
        float x = c1s[ql] + acc[i][j][r];
        float ex = __expf(2.f * x);
        float th = 1.f - 2.f / (ex + 1.f);  // tanh, saturates safely at +/-inf
        sum += Vas[ql] * th;
      }
#pragma unroll
      for (int m = 8; m > 0; m >>= 1) sum += __shfl_xor(sum, m, 16);
      if (lrow == 0) {
        int row = m0 + wm + i * 16 + ((lane >> 4) << 2) + r;
        atomicAdd(&e[row], sum);
      }
    }
  }
}

// ---------------- softmax over S per batch ---------------------------------
__global__ void softmax_kernel(const float* __restrict__ e,
                               const int* __restrict__ mask,
                               float* __restrict__ a) {
  const int b = blockIdx.x;
  const int t = threadIdx.x;
  const int lane = t & 63;
  const int w = t >> 6;
  __shared__ float red[8];
  float v[8];
  float mx = -3.0e38f;
#pragma unroll
  for (int i = 0; i < 8; i++) {
    int s = i * 256 + t;
    float x = e[(size_t)b * Sn + s];
    if (mask[(size_t)b * Sn + s] == 0) x = -1e32f;
    v[i] = x;
    mx = fmaxf(mx, x);
  }
#pragma unroll
  for (int m = 32; m > 0; m >>= 1) mx = fmaxf(mx, __shfl_xor(mx, m, 64));
  if (lane == 0) red[w] = mx;
  __syncthreads();
  mx = fmaxf(fmaxf(red[0], red[1]), fmaxf(red[2], red[3]));
  float sm = 0.f;
#pragma unroll
  for (int i = 0; i < 8; i++) {
    v[i] = __expf(v[i] - mx);
    sm += v[i];
  }
#pragma unroll
  for (int m = 32; m > 0; m >>= 1) sm += __shfl_xor(sm, m, 64);
  if (lane == 0) red[4 + w] = sm;
  __syncthreads();
  sm = red[4] + red[5] + red[6] + red[7];
  float inv = 1.f / sm;
#pragma unroll
  for (int i = 0; i < 8; i++) a[(size_t)b * Sn + i * 256 + t] = v[i] * inv;
}

// ---------------- context[b,h] = sum_s a[b,s]*rnn[b,s,h] -------------------
__global__ void ctx_kernel(const float* __restrict__ rnn,
                           const float* __restrict__ a,
                           float* __restrict__ out) {
  const int b = blockIdx.y;
  const int sc = blockIdx.x;  // s-chunk of 256
  const int t = threadIdx.x;
  __shared__ float as_[256];
  as_[t] = a[(size_t)b * Sn + sc * 256 + t];
  __syncthreads();
  float a0 = 0, a1 = 0, a2 = 0, a3 = 0, a4 = 0, a5 = 0, a6 = 0, a7 = 0;
  const float* base = rnn + ((size_t)b * Sn + sc * 256) * Hn + t * 8;
  for (int s = 0; s < 256; s++) {
    float wgt = as_[s];
    float4 v0 = *(const float4*)(base + (size_t)s * Hn);
    float4 v1 = *(const float4*)(base + (size_t)s * Hn + 4);
    a0 += wgt * v0.x; a1 += wgt * v0.y; a2 += wgt * v0.z; a3 += wgt * v0.w;
    a4 += wgt * v1.x; a5 += wgt * v1.y; a6 += wgt * v1.z; a7 += wgt * v1.w;
  }
  float* o = out + (size_t)b * Hn + t * 8;
  atomicAdd(o + 0, a0); atomicAdd(o + 1, a1);
  atomicAdd(o + 2, a2); atomicAdd(o + 3, a3);
  atomicAdd(o + 4, a4); atomicAdd(o + 5, a5);
  atomicAdd(o + 6, a6); atomicAdd(o + 7, a7);
}

extern "C" void kernel_launch(void* const* d_in, const int* in_sizes, int n_in,
                              void* d_out, int out_size, void* d_ws,
                              size_t ws_size, hipStream_t stream) {
  const float* rnn = (const float*)d_in[0];
  const float* rev = (const float*)d_in[1];
  const int* mask = (const int*)d_in[2];
  const float* Wa = (const float*)d_in[3];
  const float* Ua = (const float*)d_in[4];
  const float* Va = (const float*)d_in[5];
  float* out = (float*)d_out;

  char* w = (char*)d_ws;
  unsigned short* Uabf = (unsigned short*)w;                       // 4 MiB
  float* c1 = (float*)(w + (size_t)4 * 1024 * 1024);               // 128 KiB
  float* e = (float*)(w + (size_t)4 * 1024 * 1024 + 128 * 1024);   // 256 KiB
  float* a = (float*)(w + (size_t)4 * 1024 * 1024 + 384 * 1024);   // 256 KiB

  hipMemsetAsync(e, 0, (size_t)Mn * sizeof(float), stream);
  hipMemsetAsync(d_out, 0, (size_t)out_size * sizeof(float), stream);

  cvt_ua_kernel<<<(Qn * Hn / 4) / 256, 256, 0, stream>>>(Ua, Uabf);
  c1_kernel<<<(Bn * Qn) / 4, 256, 0, stream>>>(rev, Wa, c1);

  dim3 g(Qn / BN, Mn / BM);  // n-tiles fast -> A-panel L2 reuse
  gemm_e_kernel<<<g, 256, 0, stream>>>(rnn, Uabf, c1, Va, e);

  softmax_kernel<<<Bn, 256, 0, stream>>>(e, mask, a);

  dim3 gc(8, Bn);
  ctx_kernel<<<gc, 256, 0, stream>>>(rnn, a, out);
}

// Round 2
// 592.594 us; speedup vs baseline: 1.2181x; 1.2181x over previous
//
#include <hip/hip_runtime.h>
#include <hip/hip_bf16.h>

#define Bn 32
#define Sn 2048
#define Hn 2048
#define Qn 1024
#define Mn (Bn * Sn)

#define BM 128
#define BN 128
#define BK 64

typedef __attribute__((ext_vector_type(8))) short bf16x8;
typedef __attribute__((ext_vector_type(4))) float f32x4;

__device__ __forceinline__ unsigned short f2bf(float x) {
  unsigned int u = __float_as_uint(x);
  unsigned int r = (u + 0x7FFFu + ((u >> 16) & 1u)) >> 16;  // RNE
  return (unsigned short)r;
}

__device__ __forceinline__ unsigned int cvtpk(float lo, float hi) {
  unsigned int r;
  asm("v_cvt_pk_bf16_f32 %0, %1, %2" : "=v"(r) : "v"(lo), "v"(hi));
  return r;
}

__device__ __forceinline__ void gload16(const void* g, void* l) {
  __builtin_amdgcn_global_load_lds(
      (const __attribute__((address_space(1))) unsigned int*)g,
      (__attribute__((address_space(3))) unsigned int*)l, 16, 0, 0);
}

// ---------------- c1[b,q] = sum_k rev[b,k] * Wa[q,k] ------------------------
__global__ void c1_kernel(const float* __restrict__ rev,
                          const float* __restrict__ Wa,
                          float* __restrict__ c1) {
  int wid = (blockIdx.x * 256 + threadIdx.x) >> 6;
  int lane = threadIdx.x & 63;
  int b = wid >> 10;
  int q = wid & (Qn - 1);
  const float* rv = rev + (size_t)b * Qn;
  const float* wr = Wa + (size_t)q * Qn;
  float acc = 0.f;
#pragma unroll
  for (int k = 0; k < Qn; k += 64) acc += rv[k + lane] * wr[k + lane];
#pragma unroll
  for (int m = 32; m > 0; m >>= 1) acc += __shfl_xor(acc, m, 64);
  if (lane == 0) c1[wid] = acc;
}

// ---------------- Ua f32 -> bf16 --------------------------------------------
__global__ void cvt_ua_kernel(const float* __restrict__ Ua,
                              unsigned short* __restrict__ out) {
  int i = blockIdx.x * 256 + threadIdx.x;  // 4 elements each
  float4 v = ((const float4*)Ua)[i];
  typedef __attribute__((ext_vector_type(4))) unsigned short u16x4;
  u16x4 o = {f2bf(v.x), f2bf(v.y), f2bf(v.z), f2bf(v.w)};
  *(u16x4*)(out + (size_t)i * 4) = o;
}

// ---------------- main GEMM + fused tanh/Va epilogue ------------------------
// A = rnn [Mn,Hn] f32 (staged f32 via global_load_lds, cvt at frag read)
// Bmat = Ua bf16 [Qn,Hn] (staged via global_load_lds)
__global__ __launch_bounds__(256) void gemm_e_kernel(
    const float* __restrict__ A, const unsigned short* __restrict__ Bmat,
    const float* __restrict__ c1, const float* __restrict__ Va,
    float* __restrict__ e) {
  __shared__ alignas(128) float As_f[BM * BK];          // 32 KB, swizzled
  __shared__ alignas(128) unsigned short Bs[BN * BK];   // 16 KB, swizzled
  __shared__ float c1s[BN];
  __shared__ float Vas[BN];

  const int t = threadIdx.x;
  const int l = t & 63;
  const int w = t >> 6;

  // XCD-panel swizzle: all 8 n-tiles of an A-panel -> same XCD
  int bid = blockIdx.x;                    // 0..4095
  int swz = (bid & 7) * 512 + (bid >> 3);  // bijective (4096 % 8 == 0)
  int panel = swz >> 3;                    // 0..511
  int ntile = swz & 7;
  const int m0 = panel * BM;
  const int n0 = ntile * BN;
  const int bidx = panel >> 4;  // = m0 / 2048 (BM=128 never straddles batch)

  if (t < BN) {
    c1s[t] = c1[bidx * Qn + n0 + t];
    Vas[t] = Va[n0 + t];
  }

  const int lr4 = l >> 4;  // 0..3
  const int lr3 = l >> 3;  // 0..7

  // ---- staging source addresses (pre-swizzled global, linear LDS dest) ----
  // A tile: rows 256B (64 f32). LDS pos p=c*1024+l*16 -> r=c*4+lr4,
  // inner=(l&15)*16, stored element = inner ^ ((r&7)<<4).
  const int innerA = (l & 15) * 16;
  const int keyAe = lr4 << 4;        // q even: r&7 = lr4
  const int keyAo = (4 + lr4) << 4;  // q odd:  r&7 = 4+lr4
  const float* pAe =
      A + (size_t)(m0 + w * 32 + lr4) * Hn + ((innerA ^ keyAe) >> 2);
  const float* pAo =
      A + (size_t)(m0 + w * 32 + 4 + lr4) * Hn + ((innerA ^ keyAo) >> 2);
  // B tile: rows 128B (64 bf16). p=c*1024+l*16 -> r=c*8+lr3, inner=(l&7)*16.
  const int innerB = (l & 7) * 16;
  const int keyB = lr3 << 4;  // r&7 = lr3 uniformly
  const unsigned short* pB =
      Bmat + (size_t)(n0 + w * 32 + lr3) * Hn + ((innerB ^ keyB) >> 1);

  char* Asb = (char*)As_f;
  char* Bsb = (char*)Bs;
  char* AsW = Asb + w * 8 * 1024;  // this wave's 8 A-chunks
  char* BsW = Bsb + w * 4 * 1024;  // this wave's 4 B-chunks

  // ---- fragment read offsets (same XOR swizzle) ----
  const int wm = (w >> 1) * 64;
  const int wn = (w & 1) * 64;
  const int lrow = l & 15;
  int aoff[4], boff[4];
#pragma unroll
  for (int i = 0; i < 4; i++) {
    int r = wm + i * 16 + lrow;
    aoff[i] = (r * 256 + lr4 * 32) ^ ((r & 7) << 4);
    int rb = wn + i * 16 + lrow;
    boff[i] = (rb * 128 + lr4 * 16) ^ ((rb & 7) << 4);
  }

  f32x4 acc[4][4];
#pragma unroll
  for (int i = 0; i < 4; i++)
#pragma unroll
    for (int j = 0; j < 4; j++) acc[i][j] = (f32x4){0.f, 0.f, 0.f, 0.f};

#pragma unroll 1
  for (int kb = 0; kb < Hn; kb += BK) {
    __syncthreads();  // previous iter's LDS reads done
#pragma unroll
    for (int q2 = 0; q2 < 4; q2++) {
      gload16(pAe + (size_t)q2 * 8 * Hn, AsW + (2 * q2) * 1024);
      gload16(pAo + (size_t)q2 * 8 * Hn, AsW + (2 * q2 + 1) * 1024);
    }
#pragma unroll
    for (int q = 0; q < 4; q++) {
      gload16(pB + (size_t)q * 8 * Hn, BsW + q * 1024);
    }
    pAe += BK;
    pAo += BK;
    pB += BK;
    __syncthreads();  // vmcnt drained by compiler before barrier -> data ready

#pragma unroll
    for (int s = 0; s < 2; s++) {
      bf16x8 af[4], bfr[4];
#pragma unroll
      for (int i = 0; i < 4; i++) {
        f32x4 lo = *(const f32x4*)(Asb + (aoff[i] + s * 128));
        f32x4 hi = *(const f32x4*)(Asb + ((aoff[i] ^ 16) + s * 128));
        union { unsigned int u[4]; bf16x8 v; } tt;
        tt.u[0] = cvtpk(lo[0], lo[1]);
        tt.u[1] = cvtpk(lo[2], lo[3]);
        tt.u[2] = cvtpk(hi[0], hi[1]);
        tt.u[3] = cvtpk(hi[2], hi[3]);
        af[i] = tt.v;
      }
#pragma unroll
      for (int j = 0; j < 4; j++)
        bfr[j] = *(const bf16x8*)(Bsb + (boff[j] ^ (s * 64)));
#pragma unroll
      for (int i = 0; i < 4; i++)
#pragma unroll
        for (int j = 0; j < 4; j++)
          acc[i][j] = __builtin_amdgcn_mfma_f32_16x16x32_bf16(
              af[i], bfr[j], acc[i][j], 0, 0, 0);
    }
  }

  // epilogue: e[row] += sum over this block's 128 q of Va*tanh(c1+c2)
#pragma unroll
  for (int i = 0; i < 4; i++) {
#pragma unroll
    for (int r = 0; r < 4; r++) {
      float sum = 0.f;
#pragma unroll
      for (int j = 0; j < 4; j++) {
        int ql = wn + j * 16 + lrow;
        float x = c1s[ql] + acc[i][j][r];
        float ex = __expf(2.f * x);
        float th = 1.f - 2.f / (ex + 1.f);  // tanh, saturates safely
        sum += Vas[ql] * th;
      }
#pragma unroll
      for (int m = 8; m > 0; m >>= 1) sum += __shfl_xor(sum, m, 16);
      if (lrow == 0) {
        int row = m0 + wm + i * 16 + ((l >> 4) << 2) + r;
        atomicAdd(&e[row], sum);
      }
    }
  }
}

// ---------------- softmax over S per batch ----------------------------------
__global__ void softmax_kernel(const float* __restrict__ e,
                               const int* __restrict__ mask,
                               float* __restrict__ a) {
  const int b = blockIdx.x;
  const int t = threadIdx.x;
  const int lane = t & 63;
  const int w = t >> 6;
  __shared__ float red[8];
  float v[8];
  float mx = -3.0e38f;
#pragma unroll
  for (int i = 0; i < 8; i++) {
    int s = i * 256 + t;
    float x = e[(size_t)b * Sn + s];
    if (mask[(size_t)b * Sn + s] == 0) x = -1e32f;
    v[i] = x;
    mx = fmaxf(mx, x);
  }
#pragma unroll
  for (int m = 32; m > 0; m >>= 1) mx = fmaxf(mx, __shfl_xor(mx, m, 64));
  if (lane == 0) red[w] = mx;
  __syncthreads();
  mx = fmaxf(fmaxf(red[0], red[1]), fmaxf(red[2], red[3]));
  float sm = 0.f;
#pragma unroll
  for (int i = 0; i < 8; i++) {
    v[i] = __expf(v[i] - mx);
    sm += v[i];
  }
#pragma unroll
  for (int m = 32; m > 0; m >>= 1) sm += __shfl_xor(sm, m, 64);
  if (lane == 0) red[4 + w] = sm;
  __syncthreads();
  sm = red[4] + red[5] + red[6] + red[7];
  float inv = 1.f / sm;
#pragma unroll
  for (int i = 0; i < 8; i++) a[(size_t)b * Sn + i * 256 + t] = v[i] * inv;
}

// ---------------- context[b,h] = sum_s a[b,s]*rnn[b,s,h] --------------------
__global__ void ctx_kernel(const float* __restrict__ rnn,
                           const float* __restrict__ a,
                           float* __restrict__ out) {
  const int b = blockIdx.y;
  const int sc = blockIdx.x;  // s-chunk of 256
  const int t = threadIdx.x;
  __shared__ float as_[256];
  as_[t] = a[(size_t)b * Sn + sc * 256 + t];
  __syncthreads();
  float a0 = 0, a1 = 0, a2 = 0, a3 = 0, a4 = 0, a5 = 0, a6 = 0, a7 = 0;
  const float* base = rnn + ((size_t)b * Sn + sc * 256) * Hn + t * 8;
  for (int s = 0; s < 256; s++) {
    float wgt = as_[s];
    float4 v0 = *(const float4*)(base + (size_t)s * Hn);
    float4 v1 = *(const float4*)(base + (size_t)s * Hn + 4);
    a0 += wgt * v0.x; a1 += wgt * v0.y; a2 += wgt * v0.z; a3 += wgt * v0.w;
    a4 += wgt * v1.x; a5 += wgt * v1.y; a6 += wgt * v1.z; a7 += wgt * v1.w;
  }
  float* o = out + (size_t)b * Hn + t * 8;
  atomicAdd(o + 0, a0); atomicAdd(o + 1, a1);
  atomicAdd(o + 2, a2); atomicAdd(o + 3, a3);
  atomicAdd(o + 4, a4); atomicAdd(o + 5, a5);
  atomicAdd(o + 6, a6); atomicAdd(o + 7, a7);
}

extern "C" void kernel_launch(void* const* d_in, const int* in_sizes, int n_in,
                              void* d_out, int out_size, void* d_ws,
                              size_t ws_size, hipStream_t stream) {
  const float* rnn = (const float*)d_in[0];
  const float* rev = (const float*)d_in[1];
  const int* mask = (const int*)d_in[2];
  const float* Wa = (const float*)d_in[3];
  const float* Ua = (const float*)d_in[4];
  const float* Va = (const float*)d_in[5];

  char* w = (char*)d_ws;
  unsigned short* Uabf = (unsigned short*)w;                       // 4 MiB
  float* c1 = (float*)(w + (size_t)4 * 1024 * 1024);               // 128 KiB
  float* e = (float*)(w + (size_t)4 * 1024 * 1024 + 128 * 1024);   // 256 KiB
  float* a = (float*)(w + (size_t)4 * 1024 * 1024 + 384 * 1024);   // 256 KiB

  hipMemsetAsync(e, 0, (size_t)Mn * sizeof(float), stream);
  hipMemsetAsync(d_out, 0, (size_t)out_size * sizeof(float), stream);

  cvt_ua_kernel<<<(Qn * Hn / 4) / 256, 256, 0, stream>>>(Ua, Uabf);
  c1_kernel<<<(Bn * Qn) / 4, 256, 0, stream>>>(rev, Wa, c1);

  gemm_e_kernel<<<(Mn / BM) * (Qn / BN), 256, 0, stream>>>(rnn, Uabf, c1, Va, e);

  softmax_kernel<<<Bn, 256, 0, stream>>>(e, mask, a);

  dim3 gc(8, Bn);
  ctx_kernel<<<gc, 256, 0, stream>>>(rnn, a, (float*)d_out);
}

// Round 3
// 500.732 us; speedup vs baseline: 1.4416x; 1.1835x over previous
//
#include <hip/hip_runtime.h>
#include <hip/hip_bf16.h>

#define Bn 32
#define Sn 2048
#define Hn 2048
#define Qn 1024
#define Mn (Bn * Sn)

typedef __attribute__((ext_vector_type(8))) short bf16x8;
typedef __attribute__((ext_vector_type(4))) float f32x4;

__device__ __forceinline__ unsigned short f2bf(float x) {
  unsigned int u = __float_as_uint(x);
  unsigned int r = (u + 0x7FFFu + ((u >> 16) & 1u)) >> 16;  // RNE
  return (unsigned short)r;
}

__device__ __forceinline__ float bf2f(short s) {
  return __uint_as_float(((unsigned int)(unsigned short)s) << 16);
}

__device__ __forceinline__ unsigned int cvtpk(float lo, float hi) {
  unsigned int r;
  asm("v_cvt_pk_bf16_f32 %0, %1, %2" : "=v"(r) : "v"(lo), "v"(hi));
  return r;
}

__device__ __forceinline__ void gload16(const void* g, void* l) {
  __builtin_amdgcn_global_load_lds(
      (const __attribute__((address_space(1))) unsigned int*)g,
      (__attribute__((address_space(3))) unsigned int*)l, 16, 0, 0);
}

// ---------------- rnn f32 -> bf16 (grid-stride, 8 elems/thread/iter) --------
__global__ void cvt_rnn_kernel(const float* __restrict__ in,
                               unsigned short* __restrict__ out) {
  const size_t total8 = (size_t)Mn * Hn / 8;  // 16,777,216 chunks
  size_t i = (size_t)blockIdx.x * 256 + threadIdx.x;
  const size_t stride = (size_t)gridDim.x * 256;
  for (; i < total8; i += stride) {
    float4 v0 = ((const float4*)in)[i * 2];
    float4 v1 = ((const float4*)in)[i * 2 + 1];
    union { unsigned int u[4]; bf16x8 v; } pk;
    pk.u[0] = cvtpk(v0.x, v0.y);
    pk.u[1] = cvtpk(v0.z, v0.w);
    pk.u[2] = cvtpk(v1.x, v1.y);
    pk.u[3] = cvtpk(v1.z, v1.w);
    *(bf16x8*)(out + i * 8) = pk.v;
  }
}

// ---------------- c1[b,q] = sum_k rev[b,k] * Wa[q,k] ------------------------
__global__ void c1_kernel(const float* __restrict__ rev,
                          const float* __restrict__ Wa,
                          float* __restrict__ c1) {
  int wid = (blockIdx.x * 256 + threadIdx.x) >> 6;
  int lane = threadIdx.x & 63;
  int b = wid >> 10;
  int q = wid & (Qn - 1);
  const float* rv = rev + (size_t)b * Qn;
  const float* wr = Wa + (size_t)q * Qn;
  float acc = 0.f;
#pragma unroll
  for (int k = 0; k < Qn; k += 64) acc += rv[k + lane] * wr[k + lane];
#pragma unroll
  for (int m = 32; m > 0; m >>= 1) acc += __shfl_xor(acc, m, 64);
  if (lane == 0) c1[wid] = acc;
}

// ---------------- Ua f32 -> bf16 --------------------------------------------
__global__ void cvt_ua_kernel(const float* __restrict__ Ua,
                              unsigned short* __restrict__ out) {
  int i = blockIdx.x * 256 + threadIdx.x;  // 4 elements each
  float4 v = ((const float4*)Ua)[i];
  typedef __attribute__((ext_vector_type(4))) unsigned short u16x4;
  u16x4 o = {f2bf(v.x), f2bf(v.y), f2bf(v.z), f2bf(v.w)};
  *(u16x4*)(out + (size_t)i * 4) = o;
}

// ============================================================================
// 256x256x64 8-phase double-buffered bf16 GEMM with fused tanh/Va epilogue.
// A = rnnbf [Mn][Hn] bf16 ; Bm = Uabf [Qn][Hn] bf16 ; e[m] += Va.tanh(c1+C)
// 8 waves = 2(M) x 4(N); per-wave 128x64 output = acc[8][4] f32x4.
// LDS: A[2][256][64]bf16 (64KB) + B[2][256][64]bf16 (64KB), chunk-swizzled
//   storage slot = chunk ^ (row&7)   (16B chunks, 8 per 128B row)
// ============================================================================
#define NKT 32  // K-tiles (Hn/64)

#define STAGE_A(kt, h)                                                        \
  do {                                                                        \
    int d_ = (kt) & 1;                                                        \
    gload16(aS + (size_t)((h) * 128) * Hn + (kt) * 64,                        \
            ldsA + d_ * 32768 + (h) * 16384 + wl);                            \
    gload16(aS + (size_t)((h) * 128 + 64) * Hn + (kt) * 64,                   \
            ldsA + d_ * 32768 + (h) * 16384 + 8192 + wl);                     \
  } while (0)

#define STAGE_B(kt, h)                                                        \
  do {                                                                        \
    int d_ = (kt) & 1;                                                        \
    gload16(bS + (size_t)((h) * 128) * Hn + (kt) * 64,                        \
            ldsB + d_ * 32768 + (h) * 16384 + wl);                            \
    gload16(bS + (size_t)((h) * 128 + 64) * Hn + (kt) * 64,                   \
            ldsB + d_ * 32768 + (h) * 16384 + 8192 + wl);                     \
  } while (0)

#define VW4                                                                   \
  do {                                                                        \
    asm volatile("s_waitcnt vmcnt(4)");                                       \
    __builtin_amdgcn_sched_barrier(0);                                        \
  } while (0)
#define VW0                                                                   \
  do {                                                                        \
    asm volatile("s_waitcnt vmcnt(0)");                                       \
    __builtin_amdgcn_sched_barrier(0);                                        \
  } while (0)
#define NOPW ((void)0)

#define PHASE(d, qm, qn, ISSUE, WAITV)                                        \
  do {                                                                        \
    if ((qn) == 0) {                                                          \
      _Pragma("unroll") for (int ii = 0; ii < 4; ii++) {                      \
        afr[ii][0] = *(const bf16x8*)(ldsA + (d) * 32768 + rA +               \
                                      ((qm) * 64 + ii * 16) * 128 + cA0);     \
        afr[ii][1] = *(const bf16x8*)(ldsA + (d) * 32768 + rA +               \
                                      ((qm) * 64 + ii * 16) * 128 + cA1);     \
      }                                                                       \
    }                                                                         \
    if ((qm) == 0) {                                                          \
      _Pragma("unroll") for (int jj = 0; jj < 2; jj++) {                      \
        bfr[(qn) * 2 + jj][0] =                                               \
            *(const bf16x8*)(ldsB + (d) * 32768 + rB +                        \
                             (((qn) * 2 + jj) * 16) * 128 + cA0);             \
        bfr[(qn) * 2 + jj][1] =                                               \
            *(const bf16x8*)(ldsB + (d) * 32768 + rB +                        \
                             (((qn) * 2 + jj) * 16) * 128 + cA1);             \
      }                                                                       \
    }                                                                         \
    ISSUE;                                                                    \
    __builtin_amdgcn_s_barrier();                                             \
    asm volatile("s_waitcnt lgkmcnt(0)");                                     \
    __builtin_amdgcn_sched_barrier(0);                                        \
    __builtin_amdgcn_s_setprio(1);                                            \
    _Pragma("unroll") for (int ii = 0; ii < 4; ii++)                          \
        _Pragma("unroll") for (int jj = 0; jj < 2; jj++)                      \
            _Pragma("unroll") for (int ks = 0; ks < 2; ks++)                  \
                acc[(qm) * 4 + ii][(qn) * 2 + jj] =                           \
        __builtin_amdgcn_mfma_f32_16x16x32_bf16(                              \
            afr[ii][ks], bfr[(qn) * 2 + jj][ks],                              \
            acc[(qm) * 4 + ii][(qn) * 2 + jj], 0, 0, 0);                      \
    __builtin_amdgcn_s_setprio(0);                                            \
    WAITV;                                                                    \
    __builtin_amdgcn_s_barrier();                                             \
    __builtin_amdgcn_sched_barrier(0);                                        \
  } while (0)

__global__ __launch_bounds__(512, 2) void gemm8_kernel(
    const unsigned short* __restrict__ A, const unsigned short* __restrict__ Bm,
    const float* __restrict__ c1, const float* __restrict__ Va,
    float* __restrict__ e) {
  __shared__ __align__(128) char lds[131072];
  __shared__ float c1s[256];
  __shared__ float Vas[256];

  const int t = threadIdx.x;
  const int l = t & 63;
  const int w = t >> 6;
  const int wr = w >> 2, wc = w & 3;

  int bid = blockIdx.x;  // 1024 blocks, 1024 % 8 == 0 -> bijective XCD swizzle
  int swz = (bid & 7) * 128 + (bid >> 3);
  const int mtile = swz >> 2;
  const int ntile = swz & 3;
  const int m0 = mtile * 256, n0 = ntile * 256;
  const int bidx = mtile >> 3;  // batch (256-row tile never straddles S=2048)

  if (t < 256) {
    c1s[t] = c1[bidx * Qn + n0 + t];
    Vas[t] = Va[n0 + t];
  }

  // staging source (pre-swizzled chunk): thread t covers (row sr, slot t&7)
  const int sr = t >> 3;                    // 0..63
  const int sj = (t & 7) ^ (sr & 7);        // logical 16B-chunk index
  const unsigned short* aS = A + (size_t)(m0 + sr) * Hn + sj * 8;
  const unsigned short* bS = Bm + (size_t)(n0 + sr) * Hn + sj * 8;
  char* ldsA = lds;
  char* ldsB = lds + 65536;
  const int wl = w * 1024;

  // fragment read constants: row&7 == l&7 for all frag rows
  const int xk = l & 7;
  const int lr4 = l >> 4;
  const int cA0 = ((0 * 4 + lr4) ^ xk) * 16;
  const int cA1 = ((1 * 4 + lr4) ^ xk) * 16;
  const int rA = (wr * 128 + (l & 15)) * 128;
  const int rB = (wc * 64 + (l & 15)) * 128;

  f32x4 acc[8][4];
#pragma unroll
  for (int i = 0; i < 8; i++)
#pragma unroll
    for (int j = 0; j < 4; j++) acc[i][j] = (f32x4){0.f, 0.f, 0.f, 0.f};

  bf16x8 afr[4][2], bfr[4][2];

  // ---- prologue: buf0 = ktile0 (8 loads), buf1.B = ktile1 (4 loads) ----
  asm volatile("s_waitcnt vmcnt(0)");  // drain c1s/Vas loads from vmcnt
  __builtin_amdgcn_sched_barrier(0);
  STAGE_A(0, 0);
  STAGE_A(0, 1);
  STAGE_B(0, 0);
  STAGE_B(0, 1);
  STAGE_B(1, 0);
  STAGE_B(1, 1);
  asm volatile("s_waitcnt vmcnt(4)");  // buf0 landed; buf1.B in flight
  __builtin_amdgcn_sched_barrier(0);
  __builtin_amdgcn_s_barrier();
  __builtin_amdgcn_sched_barrier(0);

#pragma unroll 1
  for (int it = 0; it < NKT / 2; ++it) {
    const int ko = 2 * it + 1;
    const int k2 = 2 * it + 2, k3 = 2 * it + 3;
    const bool nx = (it < NKT / 2 - 1);
    // ---- even K-tile (buf0) ----
    PHASE(0, 0, 0, STAGE_A(ko, 0), NOPW);                       // ph1
    PHASE(0, 0, 1, STAGE_A(ko, 1), NOPW);                       // ph2
    PHASE(0, 1, 0, if (nx) STAGE_B(k2, 0), NOPW);               // ph3
    PHASE(0, 1, 1, if (nx) STAGE_B(k2, 1), if (nx) VW4; else VW0);  // ph4
    // ---- odd K-tile (buf1) ----
    PHASE(1, 0, 0, if (nx) STAGE_A(k2, 0), NOPW);               // ph5
    PHASE(1, 0, 1, if (nx) STAGE_A(k2, 1), NOPW);               // ph6
    PHASE(1, 1, 0, if (nx) STAGE_B(k3, 0), NOPW);               // ph7
    PHASE(1, 1, 1, if (nx) STAGE_B(k3, 1), if (nx) VW4; else VW0);  // ph8
  }

  // ---- epilogue: e[row] += sum over this block's 256 q of Va*tanh(c1+C) ----
#pragma unroll
  for (int i = 0; i < 8; i++) {
#pragma unroll
    for (int r = 0; r < 4; r++) {
      float sum = 0.f;
#pragma unroll
      for (int j = 0; j < 4; j++) {
        int ql = wc * 64 + j * 16 + (l & 15);
        float x = c1s[ql] + acc[i][j][r];
        float ex = __expf(2.f * x);
        sum += Vas[ql] * (1.f - 2.f / (ex + 1.f));
      }
#pragma unroll
      for (int m = 8; m > 0; m >>= 1) sum += __shfl_xor(sum, m, 16);
      if ((l & 15) == 0) {
        int row = m0 + wr * 128 + i * 16 + (l >> 4) * 4 + r;
        atomicAdd(&e[row], sum);
      }
    }
  }
}

// ---------------- fallback GEMM (R2, f32 A) ---------------------------------
#define BMf 128
#define BNf 128
#define BKf 64
__global__ __launch_bounds__(256) void gemm_e_kernel(
    const float* __restrict__ A, const unsigned short* __restrict__ Bmat,
    const float* __restrict__ c1, const float* __restrict__ Va,
    float* __restrict__ e) {
  __shared__ alignas(128) float As_f[BMf * BKf];
  __shared__ alignas(128) unsigned short Bs[BNf * BKf];
  __shared__ float c1s[BNf];
  __shared__ float Vas[BNf];

  const int t = threadIdx.x;
  const int l = t & 63;
  const int w = t >> 6;
  int bid = blockIdx.x;
  int swz = (bid & 7) * 512 + (bid >> 3);
  int panel = swz >> 3;
  int ntile = swz & 7;
  const int m0 = panel * BMf;
  const int n0 = ntile * BNf;
  const int bidx = panel >> 4;

  if (t < BNf) {
    c1s[t] = c1[bidx * Qn + n0 + t];
    Vas[t] = Va[n0 + t];
  }
  const int lr4 = l >> 4;
  const int lr3 = l >> 3;
  const int innerA = (l & 15) * 16;
  const int keyAe = lr4 << 4;
  const int keyAo = (4 + lr4) << 4;
  const float* pAe =
      A + (size_t)(m0 + w * 32 + lr4) * Hn + ((innerA ^ keyAe) >> 2);
  const float* pAo =
      A + (size_t)(m0 + w * 32 + 4 + lr4) * Hn + ((innerA ^ keyAo) >> 2);
  const int innerB = (l & 7) * 16;
  const int keyB = lr3 << 4;
  const unsigned short* pB =
      Bmat + (size_t)(n0 + w * 32 + lr3) * Hn + ((innerB ^ keyB) >> 1);

  char* Asb = (char*)As_f;
  char* Bsb = (char*)Bs;
  char* AsW = Asb + w * 8 * 1024;
  char* BsW = Bsb + w * 4 * 1024;

  const int wm = (w >> 1) * 64;
  const int wn = (w & 1) * 64;
  const int lrow = l & 15;
  int aoff[4], boff[4];
#pragma unroll
  for (int i = 0; i < 4; i++) {
    int r = wm + i * 16 + lrow;
    aoff[i] = (r * 256 + lr4 * 32) ^ ((r & 7) << 4);
    int rb = wn + i * 16 + lrow;
    boff[i] = (rb * 128 + lr4 * 16) ^ ((rb & 7) << 4);
  }

  f32x4 acc[4][4];
#pragma unroll
  for (int i = 0; i < 4; i++)
#pragma unroll
    for (int j = 0; j < 4; j++) acc[i][j] = (f32x4){0.f, 0.f, 0.f, 0.f};

#pragma unroll 1
  for (int kb = 0; kb < Hn; kb += BKf) {
    __syncthreads();
#pragma unroll
    for (int q2 = 0; q2 < 4; q2++) {
      gload16(pAe + (size_t)q2 * 8 * Hn, AsW + (2 * q2) * 1024);
      gload16(pAo + (size_t)q2 * 8 * Hn, AsW + (2 * q2 + 1) * 1024);
    }
#pragma unroll
    for (int q = 0; q < 4; q++) gload16(pB + (size_t)q * 8 * Hn, BsW + q * 1024);
    pAe += BKf;
    pAo += BKf;
    pB += BKf;
    __syncthreads();

#pragma unroll
    for (int s = 0; s < 2; s++) {
      bf16x8 af[4], bfv[4];
#pragma unroll
      for (int i = 0; i < 4; i++) {
        f32x4 lo = *(const f32x4*)(Asb + (aoff[i] + s * 128));
        f32x4 hi = *(const f32x4*)(Asb + ((aoff[i] ^ 16) + s * 128));
        union { unsigned int u[4]; bf16x8 v; } tt;
        tt.u[0] = cvtpk(lo[0], lo[1]);
        tt.u[1] = cvtpk(lo[2], lo[3]);
        tt.u[2] = cvtpk(hi[0], hi[1]);
        tt.u[3] = cvtpk(hi[2], hi[3]);
        af[i] = tt.v;
      }
#pragma unroll
      for (int j = 0; j < 4; j++)
        bfv[j] = *(const bf16x8*)(Bsb + (boff[j] ^ (s * 64)));
#pragma unroll
      for (int i = 0; i < 4; i++)
#pragma unroll
        for (int j = 0; j < 4; j++)
          acc[i][j] = __builtin_amdgcn_mfma_f32_16x16x32_bf16(
              af[i], bfv[j], acc[i][j], 0, 0, 0);
    }
  }

#pragma unroll
  for (int i = 0; i < 4; i++) {
#pragma unroll
    for (int r = 0; r < 4; r++) {
      float sum = 0.f;
#pragma unroll
      for (int j = 0; j < 4; j++) {
        int ql = wn + j * 16 + lrow;
        float x = c1s[ql] + acc[i][j][r];
        float ex = __expf(2.f * x);
        sum += Vas[ql] * (1.f - 2.f / (ex + 1.f));
      }
#pragma unroll
      for (int m = 8; m > 0; m >>= 1) sum += __shfl_xor(sum, m, 16);
      if (lrow == 0) {
        int row = m0 + wm + i * 16 + ((l >> 4) << 2) + r;
        atomicAdd(&e[row], sum);
      }
    }
  }
}

// ---------------- softmax over S per batch ----------------------------------
__global__ void softmax_kernel(const float* __restrict__ e,
                               const int* __restrict__ mask,
                               float* __restrict__ a) {
  const int b = blockIdx.x;
  const int t = threadIdx.x;
  const int lane = t & 63;
  const int w = t >> 6;
  __shared__ float red[8];
  float v[8];
  float mx = -3.0e38f;
#pragma unroll
  for (int i = 0; i < 8; i++) {
    int s = i * 256 + t;
    float x = e[(size_t)b * Sn + s];
    if (mask[(size_t)b * Sn + s] == 0) x = -1e32f;
    v[i] = x;
    mx = fmaxf(mx, x);
  }
#pragma unroll
  for (int m = 32; m > 0; m >>= 1) mx = fmaxf(mx, __shfl_xor(mx, m, 64));
  if (lane == 0) red[w] = mx;
  __syncthreads();
  mx = fmaxf(fmaxf(red[0], red[1]), fmaxf(red[2], red[3]));
  float sm = 0.f;
#pragma unroll
  for (int i = 0; i < 8; i++) {
    v[i] = __expf(v[i] - mx);
    sm += v[i];
  }
#pragma unroll
  for (int m = 32; m > 0; m >>= 1) sm += __shfl_xor(sm, m, 64);
  if (lane == 0) red[4 + w] = sm;
  __syncthreads();
  sm = red[4] + red[5] + red[6] + red[7];
  float inv = 1.f / sm;
#pragma unroll
  for (int i = 0; i < 8; i++) a[(size_t)b * Sn + i * 256 + t] = v[i] * inv;
}

// ---------------- context from bf16 rnn -------------------------------------
__global__ void ctx_bf16_kernel(const unsigned short* __restrict__ rnnbf,
                                const float* __restrict__ a,
                                float* __restrict__ out) {
  const int b = blockIdx.y;
  const int sc = blockIdx.x;
  const int t = threadIdx.x;
  __shared__ float as_[256];
  as_[t] = a[(size_t)b * Sn + sc * 256 + t];
  __syncthreads();
  float ac[8] = {0, 0, 0, 0, 0, 0, 0, 0};
  const unsigned short* base =
      rnnbf + ((size_t)b * Sn + sc * 256) * Hn + t * 8;
  for (int s = 0; s < 256; s++) {
    float wgt = as_[s];
    bf16x8 v = *(const bf16x8*)(base + (size_t)s * Hn);
#pragma unroll
    for (int k = 0; k < 8; k++) ac[k] += wgt * bf2f(v[k]);
  }
  float* o = out + (size_t)b * Hn + t * 8;
#pragma unroll
  for (int k = 0; k < 8; k++) atomicAdd(o + k, ac[k]);
}

// ---------------- context from f32 rnn (fallback) ---------------------------
__global__ void ctx_kernel(const float* __restrict__ rnn,
                           const float* __restrict__ a,
                           float* __restrict__ out) {
  const int b = blockIdx.y;
  const int sc = blockIdx.x;
  const int t = threadIdx.x;
  __shared__ float as_[256];
  as_[t] = a[(size_t)b * Sn + sc * 256 + t];
  __syncthreads();
  float a0 = 0, a1 = 0, a2 = 0, a3 = 0, a4 = 0, a5 = 0, a6 = 0, a7 = 0;
  const float* base = rnn + ((size_t)b * Sn + sc * 256) * Hn + t * 8;
  for (int s = 0; s < 256; s++) {
    float wgt = as_[s];
    float4 v0 = *(const float4*)(base + (size_t)s * Hn);
    float4 v1 = *(const float4*)(base + (size_t)s * Hn + 4);
    a0 += wgt * v0.x; a1 += wgt * v0.y; a2 += wgt * v0.z; a3 += wgt * v0.w;
    a4 += wgt * v1.x; a5 += wgt * v1.y; a6 += wgt * v1.z; a7 += wgt * v1.w;
  }
  float* o = out + (size_t)b * Hn + t * 8;
  atomicAdd(o + 0, a0); atomicAdd(o + 1, a1);
  atomicAdd(o + 2, a2); atomicAdd(o + 3, a3);
  atomicAdd(o + 4, a4); atomicAdd(o + 5, a5);
  atomicAdd(o + 6, a6); atomicAdd(o + 7, a7);
}

extern "C" void kernel_launch(void* const* d_in, const int* in_sizes, int n_in,
                              void* d_out, int out_size, void* d_ws,
                              size_t ws_size, hipStream_t stream) {
  const float* rnn = (const float*)d_in[0];
  const float* rev = (const float*)d_in[1];
  const int* mask = (const int*)d_in[2];
  const float* Wa = (const float*)d_in[3];
  const float* Ua = (const float*)d_in[4];
  const float* Va = (const float*)d_in[5];

  const size_t RNBF = (size_t)Mn * Hn * 2;                 // 268435456
  const size_t NEED = RNBF + 4194304 + 131072 + 262144 + 262144;

  char* w = (char*)d_ws;
  if (ws_size >= NEED) {
    unsigned short* rnnbf = (unsigned short*)w;
    unsigned short* Uabf = (unsigned short*)(w + RNBF);
    float* c1 = (float*)(w + RNBF + 4194304);
    float* e = (float*)(w + RNBF + 4194304 + 131072);
    float* a = (float*)(w + RNBF + 4194304 + 131072 + 262144);

    hipMemsetAsync(e, 0, (size_t)Mn * sizeof(float), stream);
    hipMemsetAsync(d_out, 0, (size_t)out_size * sizeof(float), stream);

    cvt_rnn_kernel<<<4096, 256, 0, stream>>>(rnn, rnnbf);
    cvt_ua_kernel<<<(Qn * Hn / 4) / 256, 256, 0, stream>>>(Ua, Uabf);
    c1_kernel<<<(Bn * Qn) / 4, 256, 0, stream>>>(rev, Wa, c1);

    gemm8_kernel<<<(Mn / 256) * (Qn / 256), 512, 0, stream>>>(rnnbf, Uabf, c1,
                                                              Va, e);
    softmax_kernel<<<Bn, 256, 0, stream>>>(e, mask, a);
    dim3 gc(8, Bn);
    ctx_bf16_kernel<<<gc, 256, 0, stream>>>(rnnbf, a, (float*)d_out);
  } else {
    unsigned short* Uabf = (unsigned short*)w;
    float* c1 = (float*)(w + (size_t)4 * 1024 * 1024);
    float* e = (float*)(w + (size_t)4 * 1024 * 1024 + 128 * 1024);
    float* a = (float*)(w + (size_t)4 * 1024 * 1024 + 384 * 1024);

    hipMemsetAsync(e, 0, (size_t)Mn * sizeof(float), stream);
    hipMemsetAsync(d_out, 0, (size_t)out_size * sizeof(float), stream);

    cvt_ua_kernel<<<(Qn * Hn / 4) / 256, 256, 0, stream>>>(Ua, Uabf);
    c1_kernel<<<(Bn * Qn) / 4, 256, 0, stream>>>(rev, Wa, c1);
    gemm_e_kernel<<<(Mn / BMf) * (Qn / BNf), 256, 0, stream>>>(rnn, Uabf, c1,
                                                               Va, e);
    softmax_kernel<<<Bn, 256, 0, stream>>>(e, mask, a);
    dim3 gc(8, Bn);
    ctx_kernel<<<gc, 256, 0, stream>>>(rnn, a, (float*)d_out);
  }
}